// Round 3
// baseline (918.929 us; speedup 1.0000x reference)
//
#include <hip/hip_runtime.h>
#include <math.h>

#define MROWS 16384   // B*N
#define DIMD  512
#define KCOD  8192
#define CAP   1048576u
#define MARGIN 9.0e-4f   // >= 2*worst-case bf16 dist err (5.6e-4) + tie window (1.3e-4)

typedef __attribute__((ext_vector_type(8))) short short8;
typedef __attribute__((ext_vector_type(4))) float f32x4;
typedef const __attribute__((address_space(1))) unsigned char glb_byte;
typedef __attribute__((address_space(3))) unsigned char lds_byte;

__device__ __forceinline__ void gload16(const void* g, void* l) {
    __builtin_amdgcn_global_load_lds((glb_byte*)g, (lds_byte*)l, 16, 0, 0);
}

__device__ __forceinline__ unsigned short f2bf(float f) {
    unsigned u = __float_as_uint(f);
    return (unsigned short)((u + 0x7FFFu + ((u >> 16) & 1u)) >> 16);   // RNE
}

// ---------------- ws layout (bytes) ----------------
#define OFF_ABF     0u           // bf16 [16384][512]  16MB
#define OFF_WBF     16777216u    // bf16 [8192][512]    8MB
#define OFF_XSQ     25165824u    // f32 [16384]
#define OFF_WSQ     25231360u    // f32 [8192]
#define OFF_THR     25264128u    // f32 [16384]  rowmin+MARGIN
#define OFF_PARTMIN 25329664u    // f32 [16384][64]     4MB
#define OFF_RES     29523968u    // u64 [16384]
#define OFF_CTCNT   29655040u    // u32 [64]
#define OFF_GCNT    29655296u    // u32
#define OFF_CTROWS  29655552u    // u16 [64][16384]     2MB
#define OFF_LIST    31752704u    // u32 [CAP]           4MB
#define OFF_PARTIAL 35947008u    // f64 [8192]
#define OFF_IDX     36012544u    // i32 [16384]
// total 36078080 <= 38174976 (proven available in rounds 1-2)

// ===================== helpers (bit-exact carryovers, passed absmax 0) =====================

__global__ __launch_bounds__(256) void sqnorms_k(const float* __restrict__ A,
                                                 const float* __restrict__ W,
                                                 float* __restrict__ xsq,
                                                 float* __restrict__ wsq)
{
    const int lane = threadIdx.x & 63;
    const int wid  = (blockIdx.x * blockDim.x + threadIdx.x) >> 6;
    const int nw   = (gridDim.x * blockDim.x) >> 6;
    for (int r = wid; r < MROWS + KCOD; r += nw) {
        const float4* src = (const float4*)((r < MROWS) ? (A + (size_t)r * DIMD)
                                                        : (W + (size_t)(r - MROWS) * DIMD));
        float4 v0 = src[lane];
        float4 v1 = src[lane + 64];
        float s = v0.x*v0.x + v0.y*v0.y + v0.z*v0.z + v0.w*v0.w
                + v1.x*v1.x + v1.y*v1.y + v1.z*v1.z + v1.w*v1.w;
        #pragma unroll
        for (int m = 1; m < 64; m <<= 1) s += __shfl_xor(s, m, 64);
        if (lane == 0) { if (r < MROWS) xsq[r] = s; else wsq[r - MROWS] = s; }
    }
}

__global__ __launch_bounds__(256) void cvt_k(const float* __restrict__ A,
                                             const float* __restrict__ W,
                                             unsigned short* __restrict__ Abf,
                                             unsigned short* __restrict__ Wbf,
                                             unsigned int* __restrict__ ctcnt,
                                             unsigned int* __restrict__ gcount)
{
    if (blockIdx.x == 0 && threadIdx.x < 65) {     // zero per-call state (no re-poison between replays)
        if (threadIdx.x < 64) ctcnt[threadIdx.x] = 0u;
        else *gcount = 0u;
    }
    const int NA4 = MROWS * DIMD / 4;      // 2097152
    const int NT4 = NA4 + KCOD * DIMD / 4; // 3145728
    for (int i = blockIdx.x * 256 + threadIdx.x; i < NT4; i += gridDim.x * 256) {
        float4 v;
        if (i < NA4) v = ((const float4*)A)[i];
        else         v = ((const float4*)W)[i - NA4];
        ushort4 o;
        o.x = f2bf(v.x); o.y = f2bf(v.y); o.z = f2bf(v.z); o.w = f2bf(v.w);
        if (i < NA4) ((ushort4*)Abf)[i] = o;
        else         ((ushort4*)Wbf)[i - NA4] = o;
    }
}

__global__ __launch_bounds__(256) void gather_k(const float* __restrict__ A,
                                                const float* __restrict__ W,
                                                const int* __restrict__ idx,
                                                float* __restrict__ out_zq,
                                                double* __restrict__ partial)
{
    __shared__ double wsum[4];
    const int t   = threadIdx.x;
    const int row = blockIdx.x * 2 + (t >> 7);
    const int col = t & 127;
    const int id  = idx[row];
    const float4 ze = ((const float4*)(A + (size_t)row * DIMD))[col];
    const float4 zq = ((const float4*)(W + (size_t)id  * DIMD))[col];
    float4 o;
    o.x = ze.x + (zq.x - ze.x);
    o.y = ze.y + (zq.y - ze.y);
    o.z = ze.z + (zq.z - ze.z);
    o.w = ze.w + (zq.w - ze.w);
    ((float4*)(out_zq + (size_t)row * DIMD))[col] = o;
    const float dx = zq.x - ze.x, dy = zq.y - ze.y, dz = zq.z - ze.z, dw = zq.w - ze.w;
    double s = (double)dx*dx + (double)dy*dy + (double)dz*dz + (double)dw*dw;
    #pragma unroll
    for (int m = 1; m < 64; m <<= 1) s += __shfl_xor(s, m, 64);
    if ((t & 63) == 0) wsum[t >> 6] = s;
    __syncthreads();
    if (t == 0) partial[blockIdx.x] = (wsum[0] + wsum[1]) + (wsum[2] + wsum[3]);
}

__global__ __launch_bounds__(256) void fin_k(const double* __restrict__ partial,
                                             float* __restrict__ outs)
{
    __shared__ double wsum[4];
    const int t = threadIdx.x;
    double s = 0.0;
    for (int i = 0; i < 32; ++i) s += partial[t + 256 * i];
    #pragma unroll
    for (int m = 1; m < 64; m <<= 1) s += __shfl_xor(s, m, 64);
    if ((t & 63) == 0) wsum[t >> 6] = s;
    __syncthreads();
    if (t == 0) {
        const double tot = (wsum[0] + wsum[1]) + (wsum[2] + wsum[3]);
        const double mse = tot / (double)((size_t)MROWS * DIMD);
        const float mf = (float)mse;
        const float vq = (float)(mse * 1.25);
        outs[0] = vq; outs[1] = mf; outs[2] = mf; outs[3] = 0.0f; outs[4] = vq;
    }
}

// ===================== main min-pass GEMM =====================
// 512 blocks = 256 row-tiles x 2 code-halves; 2 blocks/CU resident, zero turnover.
// Block: 64 rows x (32 ct-tiles of 128 codes), K=512. 4 waves (2M x 2N), wave = 32x64.
// A-fragments persistent in registers (static-indexed, kc fully unrolled).
// B double-buffered in LDS via global_load_lds; 1 barrier per chunk.
__global__ __launch_bounds__(256, 2) void minpass_k(
    const unsigned short* __restrict__ Abf,
    const unsigned short* __restrict__ Wbf,
    const float* __restrict__ wsq,
    float* __restrict__ partmin)
{
    __shared__ unsigned short Bs[2][4096];   // [buf][code*32 + k]
    __shared__ float aux[128];

    const int t    = threadIdx.x;
    const int lane = t & 63;
    const int w    = t >> 6;
    const int wm   = w >> 1, wn = w & 1;
    const int rt   = blockIdx.x >> 1;
    const int half = blockIdx.x & 1;         // bid&7 -> XCD: each XCD sees one 4MB W-half (L2-fit)
    const int r0   = rt * 64;

    // A fragments in registers: Areg[kc][mi], row = r0 + wm*32 + mi*16 + (lane&15), k = kc*32 + (lane>>4)*8
    short8 Areg[16][2];
    {
        const unsigned short* ap0 = Abf + (size_t)(r0 + wm * 32 + (lane & 15)) * DIMD + (lane >> 4) * 8;
        const unsigned short* ap1 = ap0 + (size_t)16 * DIMD;
        #pragma unroll
        for (int kc = 0; kc < 16; ++kc) {
            Areg[kc][0] = *(const short8*)(ap0 + kc * 32);
            Areg[kc][1] = *(const short8*)(ap1 + kc * 32);
        }
    }

    // B staging: thread t stages 2x16B per chunk; dest linear, src row (t>>2)/(64+t>>2), k-slot t&3
    const int srow = t >> 2;
    const int skof = (t & 3) * 8;
    {   // prologue: chunk (ct=0,kc=0) -> buf 0
        const size_t cb = (size_t)(half * 4096 + srow) * DIMD + skof;
        gload16(Wbf + cb, &Bs[0][t * 8]);
        gload16(Wbf + cb + (size_t)64 * DIMD, &Bs[0][2048 + t * 8]);
    }

    for (int ct = 0; ct < 32; ++ct) {
        const int c0 = half * 4096 + ct * 128;
        float wsqv[4];
        #pragma unroll
        for (int ni = 0; ni < 4; ++ni)
            wsqv[ni] = wsq[c0 + wn * 64 + ni * 16 + (lane & 15)];

        f32x4 acc[2][4];
        #pragma unroll
        for (int mi = 0; mi < 2; ++mi)
            #pragma unroll
            for (int ni = 0; ni < 4; ++ni) acc[mi][ni] = (f32x4){0.f, 0.f, 0.f, 0.f};

        #pragma unroll
        for (int kc = 0; kc < 16; ++kc) {
            const int cur = kc & 1;
            __syncthreads();   // drains vmcnt: buf[cur] staged; all reads of buf[cur^1] done
            int nk = kc + 1, nct = ct;
            if (nk == 16) { nk = 0; ++nct; }
            if (nct < 32) {    // prefetch next chunk into buf[cur^1]
                const size_t cb = (size_t)(half * 4096 + nct * 128 + srow) * DIMD + nk * 32 + skof;
                gload16(Wbf + cb, &Bs[cur ^ 1][t * 8]);
                gload16(Wbf + cb + (size_t)64 * DIMD, &Bs[cur ^ 1][2048 + t * 8]);
            }
            short8 b[4];
            #pragma unroll
            for (int ni = 0; ni < 4; ++ni)
                b[ni] = *(const short8*)&Bs[cur][(wn * 64 + ni * 16 + (lane & 15)) * 32 + (lane >> 4) * 8];
            #pragma unroll
            for (int mi = 0; mi < 2; ++mi)
                #pragma unroll
                for (int ni = 0; ni < 4; ++ni)
                    acc[mi][ni] = __builtin_amdgcn_mfma_f32_16x16x32_bf16(Areg[kc][mi], b[ni], acc[mi][ni], 0, 0, 0);
        }

        // per-ct epilogue: per-row min over this 128-code tile
        #pragma unroll
        for (int mi = 0; mi < 2; ++mi) {
            #pragma unroll
            for (int reg = 0; reg < 4; ++reg) {
                float m = INFINITY;
                #pragma unroll
                for (int ni = 0; ni < 4; ++ni)
                    m = fminf(m, wsqv[ni] - 2.0f * acc[mi][ni][reg]);
                #pragma unroll
                for (int s = 1; s < 16; s <<= 1)
                    m = fminf(m, __shfl_xor(m, s, 64));
                if ((lane & 15) == 0)
                    aux[wn * 64 + wm * 32 + mi * 16 + (lane >> 4) * 4 + reg] = m;
            }
        }
        __syncthreads();
        if (t < 64)
            partmin[(size_t)(r0 + t) * 64 + (half * 32 + ct)] = fminf(aux[t], aux[64 + t]);
    }
}

// ===================== qualify: rowmin/thr, bucket qualifying (row,tile) pairs =====================
__global__ __launch_bounds__(256) void qualify_k(const float* __restrict__ partmin,
                                                 float* __restrict__ rowthr,
                                                 unsigned int* __restrict__ ctcnt,
                                                 unsigned short* __restrict__ ctrows,
                                                 unsigned long long* __restrict__ res)
{
    const int r = blockIdx.x * 256 + threadIdx.x;   // grid 64
    const float4* p = (const float4*)(partmin + (size_t)r * 64);
    float m = INFINITY;
    #pragma unroll
    for (int i = 0; i < 16; ++i) {
        float4 v = p[i];
        m = fminf(m, fminf(fminf(v.x, v.y), fminf(v.z, v.w)));
    }
    const float thr = m + MARGIN;
    rowthr[r] = thr;
    res[r] = ~0ull;
    #pragma unroll
    for (int i = 0; i < 16; ++i) {
        float4 v = p[i];
        #pragma unroll
        for (int j = 0; j < 4; ++j) {
            const float pv = (j == 0) ? v.x : (j == 1) ? v.y : (j == 2) ? v.z : v.w;
            if (pv <= thr) {
                const int tile = i * 4 + j;
                const unsigned pos = atomicAdd(&ctcnt[tile], 1u);
                if (pos < 16384u) ctrows[tile * 16384 + pos] = (unsigned short)r;
            }
        }
    }
}

// ===================== sparse candidate GEMM (round-2 vqgemm structure, gathered rows) =====================
__global__ __launch_bounds__(256) void cand_k(
    const unsigned short* __restrict__ Abf,
    const unsigned short* __restrict__ Wbf,
    const float* __restrict__ wsq,
    const float* __restrict__ rowthr,
    const unsigned int* __restrict__ ctcnt,
    const unsigned short* __restrict__ ctrows,
    unsigned int* __restrict__ list,
    unsigned int* __restrict__ gcount)
{
    __shared__ unsigned short As[2][4096];
    __shared__ unsigned short Bs[2][4096];
    __shared__ int ids_lds[128];
    __shared__ float thr_lds[128];

    const int T = blockIdx.x;                  // tile 0..63, codes T*128..T*128+127
    unsigned n = ctcnt[T]; if (n > 16384u) n = 16384u;
    const unsigned base = blockIdx.y * 128;
    if (base >= n) return;

    const int t    = threadIdx.x;
    const int lane = t & 63;
    const int w    = t >> 6;
    const int wm   = w >> 1, wn = w & 1;
    const int c0   = T * 128;

    if (t < 128) {
        const int g = (base + t < n) ? (int)ctrows[T * 16384 + base + t] : -1;
        ids_lds[t] = (g < 0) ? 0 : g;
        thr_lds[t] = (g < 0) ? -INFINITY : rowthr[g];
    }
    __syncthreads();

    const int inst0 = w * 2;
    const int lrow0 = inst0 * 16 + (lane >> 2);
    const int kof   = (lane & 3) * 8;
    const unsigned short* aSrc0 = Abf + (size_t)ids_lds[lrow0] * DIMD + kof;
    const unsigned short* aSrc1 = Abf + (size_t)ids_lds[lrow0 + 16] * DIMD + kof;
    const unsigned short* bSrc0 = Wbf + (size_t)(c0 + lrow0) * DIMD + kof;
    const unsigned short* bSrc1 = bSrc0 + (size_t)16 * DIMD;

    f32x4 acc[4][4];
    #pragma unroll
    for (int mi = 0; mi < 4; ++mi)
        #pragma unroll
        for (int ni = 0; ni < 4; ++ni) acc[mi][ni] = (f32x4){0.f, 0.f, 0.f, 0.f};

    gload16(aSrc0, &As[0][inst0 * 512]);
    gload16(aSrc1, &As[0][(inst0 + 1) * 512]);
    gload16(bSrc0, &Bs[0][inst0 * 512]);
    gload16(bSrc1, &Bs[0][(inst0 + 1) * 512]);

    int cur = 0;
    for (int kc = 0; kc < 16; ++kc) {
        __syncthreads();
        if (kc + 1 < 16) {
            const int nb = cur ^ 1;
            const int ke = (kc + 1) * 32;
            gload16(aSrc0 + ke, &As[nb][inst0 * 512]);
            gload16(aSrc1 + ke, &As[nb][(inst0 + 1) * 512]);
            gload16(bSrc0 + ke, &Bs[nb][inst0 * 512]);
            gload16(bSrc1 + ke, &Bs[nb][(inst0 + 1) * 512]);
        }
        const int ko = (lane >> 4) * 8;
        short8 a[4], b[4];
        #pragma unroll
        for (int mi = 0; mi < 4; ++mi)
            a[mi] = *(const short8*)&As[cur][(wm * 64 + mi * 16 + (lane & 15)) * 32 + ko];
        #pragma unroll
        for (int ni = 0; ni < 4; ++ni)
            b[ni] = *(const short8*)&Bs[cur][(wn * 64 + ni * 16 + (lane & 15)) * 32 + ko];
        #pragma unroll
        for (int mi = 0; mi < 4; ++mi)
            #pragma unroll
            for (int ni = 0; ni < 4; ++ni)
                acc[mi][ni] = __builtin_amdgcn_mfma_f32_16x16x32_bf16(a[mi], b[ni], acc[mi][ni], 0, 0, 0);
        __syncthreads();
        cur ^= 1;
    }

    float wsqv[4];
    #pragma unroll
    for (int ni = 0; ni < 4; ++ni)
        wsqv[ni] = wsq[c0 + wn * 64 + ni * 16 + (lane & 15)];

    #pragma unroll
    for (int mi = 0; mi < 4; ++mi) {
        #pragma unroll
        for (int reg = 0; reg < 4; ++reg) {
            const int row_l = wm * 64 + mi * 16 + (lane >> 4) * 4 + reg;
            const float thr = thr_lds[row_l];
            #pragma unroll
            for (int ni = 0; ni < 4; ++ni) {
                const float d = wsqv[ni] - 2.0f * acc[mi][ni][reg];
                if (d <= thr) {
                    const unsigned k = c0 + wn * 64 + ni * 16 + (lane & 15);
                    const unsigned pk = ((unsigned)ids_lds[row_l] << 13) | k;
                    const unsigned ix = atomicAdd(gcount, 1u);
                    if (ix < CAP) list[ix] = pk;
                }
            }
        }
    }
}

// ===================== fp64-exact refine (bit-exact carryover) =====================
__global__ __launch_bounds__(256) void refine_k(const float* __restrict__ A,
                                                const float* __restrict__ W,
                                                const float* __restrict__ xsq,
                                                const float* __restrict__ wsq,
                                                const unsigned* __restrict__ list,
                                                const unsigned* __restrict__ gcount,
                                                unsigned long long* __restrict__ res)
{
    const int lane = threadIdx.x & 63;
    const int wid  = (blockIdx.x * 256 + threadIdx.x) >> 6;
    const int nw   = (gridDim.x * 256) >> 6;
    unsigned n = *gcount;
    if (n > CAP) n = CAP;
    for (unsigned i = wid; i < n; i += nw) {
        const unsigned pk = list[i];
        const unsigned row = pk >> 13, k = pk & 8191u;
        const float4* xp = (const float4*)(A + (size_t)row * DIMD);
        const float4* wp = (const float4*)(W + (size_t)k * DIMD);
        const float4 x0 = xp[lane * 2], x1 = xp[lane * 2 + 1];
        const float4 w0 = wp[lane * 2], w1 = wp[lane * 2 + 1];
        double s = (double)x0.x * w0.x + (double)x0.y * w0.y
                 + (double)x0.z * w0.z + (double)x0.w * w0.w
                 + (double)x1.x * w1.x + (double)x1.y * w1.y
                 + (double)x1.z * w1.z + (double)x1.w * w1.w;
        #pragma unroll
        for (int m = 1; m < 64; m <<= 1) s += __shfl_xor(s, m, 64);
        if (lane == 0) {
            const float Df = (float)s;
            const float dist = (xsq[row] + wsq[k]) - 2.0f * Df;
            const unsigned long long p =
                ((unsigned long long)__float_as_uint(dist) << 32) | (unsigned long long)k;
            atomicMin(res + row, p);
        }
    }
}

__global__ __launch_bounds__(256) void finish_k(const unsigned long long* __restrict__ res,
                                                int* __restrict__ idxo,
                                                float* __restrict__ out_ids)
{
    const int r = blockIdx.x * 256 + threadIdx.x;
    const int id = (int)(res[r] & 8191ull);
    idxo[r] = id;
    out_ids[r] = (float)id;
}

// ===================== launch =====================

extern "C" void kernel_launch(void* const* d_in, const int* in_sizes, int n_in,
                              void* d_out, int out_size, void* d_ws, size_t ws_size,
                              hipStream_t stream)
{
    const float* A = (const float*)d_in[0];
    const float* W = (const float*)d_in[1];

    char* ws = (char*)d_ws;
    unsigned short* Abf = (unsigned short*)(ws + OFF_ABF);
    unsigned short* Wbf = (unsigned short*)(ws + OFF_WBF);
    float*  xsq     = (float*)(ws + OFF_XSQ);
    float*  wsq     = (float*)(ws + OFF_WSQ);
    float*  rowthr  = (float*)(ws + OFF_THR);
    float*  partmin = (float*)(ws + OFF_PARTMIN);
    unsigned long long* res = (unsigned long long*)(ws + OFF_RES);
    unsigned int* ctcnt     = (unsigned int*)(ws + OFF_CTCNT);
    unsigned int* gcount    = (unsigned int*)(ws + OFF_GCNT);
    unsigned short* ctrows  = (unsigned short*)(ws + OFF_CTROWS);
    unsigned int* list      = (unsigned int*)(ws + OFF_LIST);
    double* partial = (double*)(ws + OFF_PARTIAL);
    int*    idx     = (int*)(ws + OFF_IDX);

    float* out_zq  = (float*)d_out;
    float* out_ids = out_zq + (size_t)MROWS * DIMD;
    float* out_sc  = out_ids + MROWS;

    cvt_k<<<2048, 256, 0, stream>>>(A, W, Abf, Wbf, ctcnt, gcount);
    sqnorms_k<<<512, 256, 0, stream>>>(A, W, xsq, wsq);
    minpass_k<<<512, 256, 0, stream>>>(Abf, Wbf, wsq, partmin);
    qualify_k<<<64, 256, 0, stream>>>(partmin, rowthr, ctcnt, ctrows, res);
    cand_k<<<dim3(64, 128), 256, 0, stream>>>(Abf, Wbf, wsq, rowthr, ctcnt, ctrows, list, gcount);
    refine_k<<<512, 256, 0, stream>>>(A, W, xsq, wsq, list, gcount, res);
    finish_k<<<64, 256, 0, stream>>>(res, idx, out_ids);
    gather_k<<<8192, 256, 0, stream>>>(A, W, idx, out_zq, partial);
    fin_k<<<1, 256, 0, stream>>>(partial, out_sc);
}

// Round 4
// 342.290 us; speedup vs baseline: 2.6846x; 2.6846x over previous
//
#include <hip/hip_runtime.h>
#include <math.h>

#define MROWS 16384   // B*N
#define DIMD  512
#define KCOD  8192
#define CAP   1048576u
#define MARGIN 9.0e-4f   // >= 2*worst-case bf16 dist err (5.6e-4) + tie window (1.3e-4)

typedef __attribute__((ext_vector_type(8))) short short8;
typedef __attribute__((ext_vector_type(4))) float f32x4;
typedef const __attribute__((address_space(1))) unsigned char glb_byte;
typedef __attribute__((address_space(3))) unsigned char lds_byte;

__device__ __forceinline__ void gload16(const void* g, void* l) {
    __builtin_amdgcn_global_load_lds((glb_byte*)g, (lds_byte*)l, 16, 0, 0);
}

__device__ __forceinline__ unsigned short f2bf(float f) {
    unsigned u = __float_as_uint(f);
    return (unsigned short)((u + 0x7FFFu + ((u >> 16) & 1u)) >> 16);   // RNE
}

// ---------------- ws layout (bytes) ----------------
#define OFF_ABF     0u           // bf16 [16384][512]  16MB
#define OFF_WBF     16777216u    // bf16 [8192][512]    8MB
#define OFF_XSQ     25165824u    // f32 [16384]
#define OFF_WSQ     25231360u    // f32 [8192]
#define OFF_THR     25264128u    // f32 [16384]  rowmin+MARGIN
#define OFF_PARTMIN 25329664u    // f32 [16384][64]     4MB
#define OFF_RES     29523968u    // u64 [16384]
#define OFF_CTCNT   29655040u    // u32 [64]
#define OFF_GCNT    29655296u    // u32
#define OFF_CTROWS  29655552u    // u16 [64][16384]     2MB
#define OFF_LIST    31752704u    // u32 [CAP]           4MB
#define OFF_PARTIAL 35947008u    // f64 [8192]
#define OFF_IDX     36012544u    // i32 [16384]

// ===================== helpers (bit-exact carryovers, passed absmax 0) =====================

__global__ __launch_bounds__(256) void sqnorms_k(const float* __restrict__ A,
                                                 const float* __restrict__ W,
                                                 float* __restrict__ xsq,
                                                 float* __restrict__ wsq)
{
    const int lane = threadIdx.x & 63;
    const int wid  = (blockIdx.x * blockDim.x + threadIdx.x) >> 6;
    const int nw   = (gridDim.x * blockDim.x) >> 6;
    for (int r = wid; r < MROWS + KCOD; r += nw) {
        const float4* src = (const float4*)((r < MROWS) ? (A + (size_t)r * DIMD)
                                                        : (W + (size_t)(r - MROWS) * DIMD));
        float4 v0 = src[lane];
        float4 v1 = src[lane + 64];
        float s = v0.x*v0.x + v0.y*v0.y + v0.z*v0.z + v0.w*v0.w
                + v1.x*v1.x + v1.y*v1.y + v1.z*v1.z + v1.w*v1.w;
        #pragma unroll
        for (int m = 1; m < 64; m <<= 1) s += __shfl_xor(s, m, 64);
        if (lane == 0) { if (r < MROWS) xsq[r] = s; else wsq[r - MROWS] = s; }
    }
}

__global__ __launch_bounds__(256) void cvt_k(const float* __restrict__ A,
                                             const float* __restrict__ W,
                                             unsigned short* __restrict__ Abf,
                                             unsigned short* __restrict__ Wbf,
                                             unsigned int* __restrict__ ctcnt,
                                             unsigned int* __restrict__ gcount)
{
    if (blockIdx.x == 0 && threadIdx.x < 65) {     // zero per-call state (no re-poison between replays)
        if (threadIdx.x < 64) ctcnt[threadIdx.x] = 0u;
        else *gcount = 0u;
    }
    const int NA4 = MROWS * DIMD / 4;      // 2097152
    const int NT4 = NA4 + KCOD * DIMD / 4; // 3145728
    for (int i = blockIdx.x * 256 + threadIdx.x; i < NT4; i += gridDim.x * 256) {
        float4 v;
        if (i < NA4) v = ((const float4*)A)[i];
        else         v = ((const float4*)W)[i - NA4];
        ushort4 o;
        o.x = f2bf(v.x); o.y = f2bf(v.y); o.z = f2bf(v.z); o.w = f2bf(v.w);
        if (i < NA4) ((ushort4*)Abf)[i] = o;
        else         ((ushort4*)Wbf)[i - NA4] = o;
    }
}

__global__ __launch_bounds__(256) void gather_k(const float* __restrict__ A,
                                                const float* __restrict__ W,
                                                const int* __restrict__ idx,
                                                float* __restrict__ out_zq,
                                                double* __restrict__ partial)
{
    __shared__ double wsum[4];
    const int t   = threadIdx.x;
    const int row = blockIdx.x * 2 + (t >> 7);
    const int col = t & 127;
    const int id  = idx[row];
    const float4 ze = ((const float4*)(A + (size_t)row * DIMD))[col];
    const float4 zq = ((const float4*)(W + (size_t)id  * DIMD))[col];
    float4 o;
    o.x = ze.x + (zq.x - ze.x);
    o.y = ze.y + (zq.y - ze.y);
    o.z = ze.z + (zq.z - ze.z);
    o.w = ze.w + (zq.w - ze.w);
    ((float4*)(out_zq + (size_t)row * DIMD))[col] = o;
    const float dx = zq.x - ze.x, dy = zq.y - ze.y, dz = zq.z - ze.z, dw = zq.w - ze.w;
    double s = (double)dx*dx + (double)dy*dy + (double)dz*dz + (double)dw*dw;
    #pragma unroll
    for (int m = 1; m < 64; m <<= 1) s += __shfl_xor(s, m, 64);
    if ((t & 63) == 0) wsum[t >> 6] = s;
    __syncthreads();
    if (t == 0) partial[blockIdx.x] = (wsum[0] + wsum[1]) + (wsum[2] + wsum[3]);
}

__global__ __launch_bounds__(256) void fin_k(const double* __restrict__ partial,
                                             float* __restrict__ outs)
{
    __shared__ double wsum[4];
    const int t = threadIdx.x;
    double s = 0.0;
    for (int i = 0; i < 32; ++i) s += partial[t + 256 * i];
    #pragma unroll
    for (int m = 1; m < 64; m <<= 1) s += __shfl_xor(s, m, 64);
    if ((t & 63) == 0) wsum[t >> 6] = s;
    __syncthreads();
    if (t == 0) {
        const double tot = (wsum[0] + wsum[1]) + (wsum[2] + wsum[3]);
        const double mse = tot / (double)((size_t)MROWS * DIMD);
        const float mf = (float)mse;
        const float vq = (float)(mse * 1.25);
        outs[0] = vq; outs[1] = mf; outs[2] = mf; outs[3] = 0.0f; outs[4] = vq;
    }
}

// ===================== main min-pass GEMM (unchanged from round 3) =====================
__global__ __launch_bounds__(256, 2) void minpass_k(
    const unsigned short* __restrict__ Abf,
    const unsigned short* __restrict__ Wbf,
    const float* __restrict__ wsq,
    float* __restrict__ partmin)
{
    __shared__ unsigned short Bs[2][4096];   // [buf][code*32 + k]
    __shared__ float aux[128];

    const int t    = threadIdx.x;
    const int lane = t & 63;
    const int w    = t >> 6;
    const int wm   = w >> 1, wn = w & 1;
    const int rt   = blockIdx.x >> 1;
    const int half = blockIdx.x & 1;
    const int r0   = rt * 64;

    short8 Areg[16][2];
    {
        const unsigned short* ap0 = Abf + (size_t)(r0 + wm * 32 + (lane & 15)) * DIMD + (lane >> 4) * 8;
        const unsigned short* ap1 = ap0 + (size_t)16 * DIMD;
        #pragma unroll
        for (int kc = 0; kc < 16; ++kc) {
            Areg[kc][0] = *(const short8*)(ap0 + kc * 32);
            Areg[kc][1] = *(const short8*)(ap1 + kc * 32);
        }
    }

    const int srow = t >> 2;
    const int skof = (t & 3) * 8;
    {
        const size_t cb = (size_t)(half * 4096 + srow) * DIMD + skof;
        gload16(Wbf + cb, &Bs[0][t * 8]);
        gload16(Wbf + cb + (size_t)64 * DIMD, &Bs[0][2048 + t * 8]);
    }

    for (int ct = 0; ct < 32; ++ct) {
        const int c0 = half * 4096 + ct * 128;
        float wsqv[4];
        #pragma unroll
        for (int ni = 0; ni < 4; ++ni)
            wsqv[ni] = wsq[c0 + wn * 64 + ni * 16 + (lane & 15)];

        f32x4 acc[2][4];
        #pragma unroll
        for (int mi = 0; mi < 2; ++mi)
            #pragma unroll
            for (int ni = 0; ni < 4; ++ni) acc[mi][ni] = (f32x4){0.f, 0.f, 0.f, 0.f};

        #pragma unroll
        for (int kc = 0; kc < 16; ++kc) {
            const int cur = kc & 1;
            __syncthreads();
            int nk = kc + 1, nct = ct;
            if (nk == 16) { nk = 0; ++nct; }
            if (nct < 32) {
                const size_t cb = (size_t)(half * 4096 + nct * 128 + srow) * DIMD + nk * 32 + skof;
                gload16(Wbf + cb, &Bs[cur ^ 1][t * 8]);
                gload16(Wbf + cb + (size_t)64 * DIMD, &Bs[cur ^ 1][2048 + t * 8]);
            }
            short8 b[4];
            #pragma unroll
            for (int ni = 0; ni < 4; ++ni)
                b[ni] = *(const short8*)&Bs[cur][(wn * 64 + ni * 16 + (lane & 15)) * 32 + (lane >> 4) * 8];
            #pragma unroll
            for (int mi = 0; mi < 2; ++mi)
                #pragma unroll
                for (int ni = 0; ni < 4; ++ni)
                    acc[mi][ni] = __builtin_amdgcn_mfma_f32_16x16x32_bf16(Areg[kc][mi], b[ni], acc[mi][ni], 0, 0, 0);
        }

        #pragma unroll
        for (int mi = 0; mi < 2; ++mi) {
            #pragma unroll
            for (int reg = 0; reg < 4; ++reg) {
                float m = INFINITY;
                #pragma unroll
                for (int ni = 0; ni < 4; ++ni)
                    m = fminf(m, wsqv[ni] - 2.0f * acc[mi][ni][reg]);
                #pragma unroll
                for (int s = 1; s < 16; s <<= 1)
                    m = fminf(m, __shfl_xor(m, s, 64));
                if ((lane & 15) == 0)
                    aux[wn * 64 + wm * 32 + mi * 16 + (lane >> 4) * 4 + reg] = m;
            }
        }
        __syncthreads();
        if (t < 64)
            partmin[(size_t)(r0 + t) * 64 + (half * 32 + ct)] = fminf(aux[t], aux[64 + t]);
    }
}

// ===================== qualify v2: block-aggregated bucket append =====================
__global__ __launch_bounds__(256) void qualify_k(const float* __restrict__ partmin,
                                                 float* __restrict__ rowthr,
                                                 unsigned int* __restrict__ ctcnt,
                                                 unsigned short* __restrict__ ctrows,
                                                 unsigned long long* __restrict__ res)
{
    __shared__ unsigned cntA[64], baseL[64], cntB[64];
    const int t = threadIdx.x;
    const int r = blockIdx.x * 256 + t;   // grid 64

    if (t < 64) { cntA[t] = 0u; cntB[t] = 0u; }

    float4 v[16];
    const float4* p = (const float4*)(partmin + (size_t)r * 64);
    float m = INFINITY;
    #pragma unroll
    for (int i = 0; i < 16; ++i) {
        v[i] = p[i];
        m = fminf(m, fminf(fminf(v[i].x, v[i].y), fminf(v[i].z, v[i].w)));
    }
    const float thr = m + MARGIN;
    rowthr[r] = thr;
    res[r] = ~0ull;

    unsigned long long qm = 0ull;
    #pragma unroll
    for (int i = 0; i < 16; ++i) {
        if (v[i].x <= thr) qm |= 1ull << (i * 4 + 0);
        if (v[i].y <= thr) qm |= 1ull << (i * 4 + 1);
        if (v[i].z <= thr) qm |= 1ull << (i * 4 + 2);
        if (v[i].w <= thr) qm |= 1ull << (i * 4 + 3);
    }
    __syncthreads();
    // phase A: LDS histogram
    unsigned long long mm = qm;
    while (mm) {
        const int tile = __ffsll((long long)mm) - 1;
        mm &= mm - 1;
        atomicAdd(&cntA[tile], 1u);
    }
    __syncthreads();
    // one global atomic per (block, tile): <=64 per address, no hot line
    if (t < 64) baseL[t] = cntA[t] ? atomicAdd(&ctcnt[t], cntA[t]) : 0u;
    __syncthreads();
    // phase B: scatter via LDS offsets
    mm = qm;
    while (mm) {
        const int tile = __ffsll((long long)mm) - 1;
        mm &= mm - 1;
        const unsigned pos = baseL[tile] + atomicAdd(&cntB[tile], 1u);
        ctrows[tile * 16384 + pos] = (unsigned short)r;
    }
}

// ===================== sparse candidate GEMM v2: block-aggregated list append =====================
__global__ __launch_bounds__(256) void cand_k(
    const unsigned short* __restrict__ Abf,
    const unsigned short* __restrict__ Wbf,
    const float* __restrict__ wsq,
    const float* __restrict__ rowthr,
    const unsigned int* __restrict__ ctcnt,
    const unsigned short* __restrict__ ctrows,
    unsigned int* __restrict__ list,
    unsigned int* __restrict__ gcount)
{
    __shared__ unsigned short As[2][4096];
    __shared__ unsigned short Bs[2][4096];
    __shared__ int ids_lds[128];
    __shared__ float thr_lds[128];
    __shared__ unsigned wtot[4];
    __shared__ unsigned gb_lds;

    const int T = blockIdx.x;                  // tile 0..63, codes T*128..T*128+127
    unsigned n = ctcnt[T]; if (n > 16384u) n = 16384u;
    const unsigned base = blockIdx.y * 128;
    if (base >= n) return;

    const int t    = threadIdx.x;
    const int lane = t & 63;
    const int w    = t >> 6;
    const int wm   = w >> 1, wn = w & 1;
    const int c0   = T * 128;

    if (t < 128) {
        const int g = (base + t < n) ? (int)ctrows[T * 16384 + base + t] : -1;
        ids_lds[t] = (g < 0) ? 0 : g;
        thr_lds[t] = (g < 0) ? -INFINITY : rowthr[g];
    }
    __syncthreads();

    const int inst0 = w * 2;
    const int lrow0 = inst0 * 16 + (lane >> 2);
    const int kof   = (lane & 3) * 8;
    const unsigned short* aSrc0 = Abf + (size_t)ids_lds[lrow0] * DIMD + kof;
    const unsigned short* aSrc1 = Abf + (size_t)ids_lds[lrow0 + 16] * DIMD + kof;
    const unsigned short* bSrc0 = Wbf + (size_t)(c0 + lrow0) * DIMD + kof;
    const unsigned short* bSrc1 = bSrc0 + (size_t)16 * DIMD;

    f32x4 acc[4][4];
    #pragma unroll
    for (int mi = 0; mi < 4; ++mi)
        #pragma unroll
        for (int ni = 0; ni < 4; ++ni) acc[mi][ni] = (f32x4){0.f, 0.f, 0.f, 0.f};

    gload16(aSrc0, &As[0][inst0 * 512]);
    gload16(aSrc1, &As[0][(inst0 + 1) * 512]);
    gload16(bSrc0, &Bs[0][inst0 * 512]);
    gload16(bSrc1, &Bs[0][(inst0 + 1) * 512]);

    int cur = 0;
    for (int kc = 0; kc < 16; ++kc) {
        __syncthreads();
        if (kc + 1 < 16) {
            const int nb = cur ^ 1;
            const int ke = (kc + 1) * 32;
            gload16(aSrc0 + ke, &As[nb][inst0 * 512]);
            gload16(aSrc1 + ke, &As[nb][(inst0 + 1) * 512]);
            gload16(bSrc0 + ke, &Bs[nb][inst0 * 512]);
            gload16(bSrc1 + ke, &Bs[nb][(inst0 + 1) * 512]);
        }
        const int ko = (lane >> 4) * 8;
        short8 a[4], b[4];
        #pragma unroll
        for (int mi = 0; mi < 4; ++mi)
            a[mi] = *(const short8*)&As[cur][(wm * 64 + mi * 16 + (lane & 15)) * 32 + ko];
        #pragma unroll
        for (int ni = 0; ni < 4; ++ni)
            b[ni] = *(const short8*)&Bs[cur][(wn * 64 + ni * 16 + (lane & 15)) * 32 + ko];
        #pragma unroll
        for (int mi = 0; mi < 4; ++mi)
            #pragma unroll
            for (int ni = 0; ni < 4; ++ni)
                acc[mi][ni] = __builtin_amdgcn_mfma_f32_16x16x32_bf16(a[mi], b[ni], acc[mi][ni], 0, 0, 0);
        __syncthreads();
        cur ^= 1;
    }

    float wsqv[4];
    #pragma unroll
    for (int ni = 0; ni < 4; ++ni)
        wsqv[ni] = wsq[c0 + wn * 64 + ni * 16 + (lane & 15)];

    // phase A: count hits (no memory traffic)
    unsigned nh = 0;
    #pragma unroll
    for (int mi = 0; mi < 4; ++mi)
        #pragma unroll
        for (int reg = 0; reg < 4; ++reg) {
            const float thr = thr_lds[wm * 64 + mi * 16 + (lane >> 4) * 4 + reg];
            #pragma unroll
            for (int ni = 0; ni < 4; ++ni)
                if (wsqv[ni] - 2.0f * acc[mi][ni][reg] <= thr) ++nh;
        }

    // wave-inclusive prefix scan, block reservation (one global atomic per busy block)
    unsigned pfx = nh;
    #pragma unroll
    for (int s = 1; s < 64; s <<= 1) {
        unsigned v = __shfl_up(pfx, s, 64);
        if (lane >= s) pfx += v;
    }
    if (lane == 63) wtot[w] = pfx;
    __syncthreads();
    if (t == 0) {
        const unsigned tot = wtot[0] + wtot[1] + wtot[2] + wtot[3];
        gb_lds = tot ? atomicAdd(gcount, tot) : 0u;
    }
    __syncthreads();
    unsigned wb = 0;
    #pragma unroll
    for (int i = 0; i < 4; ++i) if (i < w) wb += wtot[i];
    unsigned myoff = gb_lds + wb + pfx - nh;   // exclusive offset

    // phase B: recompute in identical order, write
    #pragma unroll
    for (int mi = 0; mi < 4; ++mi)
        #pragma unroll
        for (int reg = 0; reg < 4; ++reg) {
            const int row_l = wm * 64 + mi * 16 + (lane >> 4) * 4 + reg;
            const float thr = thr_lds[row_l];
            #pragma unroll
            for (int ni = 0; ni < 4; ++ni) {
                if (wsqv[ni] - 2.0f * acc[mi][ni][reg] <= thr) {
                    const unsigned k = c0 + wn * 64 + ni * 16 + (lane & 15);
                    if (myoff < CAP)
                        list[myoff] = ((unsigned)ids_lds[row_l] << 13) | k;
                    ++myoff;
                }
            }
        }
}

// ===================== fp64-exact refine (bit-exact carryover) =====================
__global__ __launch_bounds__(256) void refine_k(const float* __restrict__ A,
                                                const float* __restrict__ W,
                                                const float* __restrict__ xsq,
                                                const float* __restrict__ wsq,
                                                const unsigned* __restrict__ list,
                                                const unsigned* __restrict__ gcount,
                                                unsigned long long* __restrict__ res)
{
    const int lane = threadIdx.x & 63;
    const int wid  = (blockIdx.x * 256 + threadIdx.x) >> 6;
    const int nw   = (gridDim.x * 256) >> 6;
    unsigned n = *gcount;
    if (n > CAP) n = CAP;
    for (unsigned i = wid; i < n; i += nw) {
        const unsigned pk = list[i];
        const unsigned row = pk >> 13, k = pk & 8191u;
        const float4* xp = (const float4*)(A + (size_t)row * DIMD);
        const float4* wp = (const float4*)(W + (size_t)k * DIMD);
        const float4 x0 = xp[lane * 2], x1 = xp[lane * 2 + 1];
        const float4 w0 = wp[lane * 2], w1 = wp[lane * 2 + 1];
        double s = (double)x0.x * w0.x + (double)x0.y * w0.y
                 + (double)x0.z * w0.z + (double)x0.w * w0.w
                 + (double)x1.x * w1.x + (double)x1.y * w1.y
                 + (double)x1.z * w1.z + (double)x1.w * w1.w;
        #pragma unroll
        for (int m = 1; m < 64; m <<= 1) s += __shfl_xor(s, m, 64);
        if (lane == 0) {
            const float Df = (float)s;
            const float dist = (xsq[row] + wsq[k]) - 2.0f * Df;
            const unsigned long long p =
                ((unsigned long long)__float_as_uint(dist) << 32) | (unsigned long long)k;
            atomicMin(res + row, p);
        }
    }
}

__global__ __launch_bounds__(256) void finish_k(const unsigned long long* __restrict__ res,
                                                int* __restrict__ idxo,
                                                float* __restrict__ out_ids)
{
    const int r = blockIdx.x * 256 + threadIdx.x;
    const int id = (int)(res[r] & 8191ull);
    idxo[r] = id;
    out_ids[r] = (float)id;
}

// ===================== launch =====================

extern "C" void kernel_launch(void* const* d_in, const int* in_sizes, int n_in,
                              void* d_out, int out_size, void* d_ws, size_t ws_size,
                              hipStream_t stream)
{
    const float* A = (const float*)d_in[0];
    const float* W = (const float*)d_in[1];

    char* ws = (char*)d_ws;
    unsigned short* Abf = (unsigned short*)(ws + OFF_ABF);
    unsigned short* Wbf = (unsigned short*)(ws + OFF_WBF);
    float*  xsq     = (float*)(ws + OFF_XSQ);
    float*  wsq     = (float*)(ws + OFF_WSQ);
    float*  rowthr  = (float*)(ws + OFF_THR);
    float*  partmin = (float*)(ws + OFF_PARTMIN);
    unsigned long long* res = (unsigned long long*)(ws + OFF_RES);
    unsigned int* ctcnt     = (unsigned int*)(ws + OFF_CTCNT);
    unsigned int* gcount    = (unsigned int*)(ws + OFF_GCNT);
    unsigned short* ctrows  = (unsigned short*)(ws + OFF_CTROWS);
    unsigned int* list      = (unsigned int*)(ws + OFF_LIST);
    double* partial = (double*)(ws + OFF_PARTIAL);
    int*    idx     = (int*)(ws + OFF_IDX);

    float* out_zq  = (float*)d_out;
    float* out_ids = out_zq + (size_t)MROWS * DIMD;
    float* out_sc  = out_ids + MROWS;

    cvt_k<<<2048, 256, 0, stream>>>(A, W, Abf, Wbf, ctcnt, gcount);
    sqnorms_k<<<512, 256, 0, stream>>>(A, W, xsq, wsq);
    minpass_k<<<512, 256, 0, stream>>>(Abf, Wbf, wsq, partmin);
    qualify_k<<<64, 256, 0, stream>>>(partmin, rowthr, ctcnt, ctrows, res);
    cand_k<<<dim3(64, 128), 256, 0, stream>>>(Abf, Wbf, wsq, rowthr, ctcnt, ctrows, list, gcount);
    refine_k<<<512, 256, 0, stream>>>(A, W, xsq, wsq, list, gcount, res);
    finish_k<<<64, 256, 0, stream>>>(res, idx, out_ids);
    gather_k<<<8192, 256, 0, stream>>>(A, W, idx, out_zq, partial);
    fin_k<<<1, 256, 0, stream>>>(partial, out_sc);
}

// Round 5
// 304.156 us; speedup vs baseline: 3.0212x; 1.1254x over previous
//
#include <hip/hip_runtime.h>
#include <math.h>

#define MROWS 16384   // B*N
#define DIMD  512
#define KCOD  8192
#define CAP   524224u
#define MARGIN 9.0e-4f   // >= 4*dot-err (5.6e-4) + tie window (1.3e-4) + wsq range (8e-6)

typedef __attribute__((ext_vector_type(8))) short short8;
typedef __attribute__((ext_vector_type(4))) float f32x4;
typedef const __attribute__((address_space(1))) unsigned char glb_byte;
typedef __attribute__((address_space(3))) unsigned char lds_byte;

__device__ __forceinline__ void gload16(const void* g, void* l) {
    __builtin_amdgcn_global_load_lds((glb_byte*)g, (lds_byte*)l, 16, 0, 0);
}

__device__ __forceinline__ unsigned short f2bf(float f) {
    unsigned u = __float_as_uint(f);
    return (unsigned short)((u + 0x7FFFu + ((u >> 16) & 1u)) >> 16);   // RNE
}

// ---------------- ws layout (bytes); total 38174784 <= 38174976 (proven available) ----------------
#define OFF_ABF     0u           // bf16 [16384][512]  16MB
#define OFF_WBF     16777216u    // bf16 [8192][512]    8MB
#define OFF_XSQ     25165824u    // f32 [16384]
#define OFF_WSQ     25231360u    // f32 [8192]
#define OFF_THR     25264128u    // f32 [16384]  rowmin+MARGIN
#define OFF_PM2     25329664u    // f32 [16384][128]    8MB
#define OFF_RES     33718272u    // u64 [16384]
#define OFF_CTCNT   33849344u    // u32 [64]
#define OFF_GCNT    33849600u    // u32
#define OFF_CTROWS  33849664u    // u16 [64][16384]     2MB
#define OFF_LIST    35946816u    // u32 [CAP]
#define OFF_PARTIAL 38043712u    // f64 [8192]
#define OFF_IDX     38109248u    // i32 [16384]

// ===================== fused cvt + sqnorms (summation tree bit-identical to prior rounds) =====================
__global__ __launch_bounds__(256) void cvt2_k(const float* __restrict__ A,
                                              const float* __restrict__ W,
                                              unsigned short* __restrict__ Abf,
                                              unsigned short* __restrict__ Wbf,
                                              float* __restrict__ xsq,
                                              float* __restrict__ wsq,
                                              unsigned int* __restrict__ ctcnt,
                                              unsigned int* __restrict__ gcount)
{
    if (blockIdx.x == 0 && threadIdx.x < 65) {     // zero per-call state (no re-poison between replays)
        if (threadIdx.x < 64) ctcnt[threadIdx.x] = 0u;
        else *gcount = 0u;
    }
    const int lane = threadIdx.x & 63;
    const int wid  = (blockIdx.x * blockDim.x + threadIdx.x) >> 6;
    const int nw   = (gridDim.x * blockDim.x) >> 6;
    for (int r = wid; r < MROWS + KCOD; r += nw) {
        const bool isA = (r < MROWS);
        const float4* src = (const float4*)(isA ? (A + (size_t)r * DIMD)
                                                : (W + (size_t)(r - MROWS) * DIMD));
        unsigned short* dst = isA ? (Abf + (size_t)r * DIMD)
                                  : (Wbf + (size_t)(r - MROWS) * DIMD);
        float4 v0 = src[lane];
        float4 v1 = src[lane + 64];
        ushort4 o0; o0.x = f2bf(v0.x); o0.y = f2bf(v0.y); o0.z = f2bf(v0.z); o0.w = f2bf(v0.w);
        ushort4 o1; o1.x = f2bf(v1.x); o1.y = f2bf(v1.y); o1.z = f2bf(v1.z); o1.w = f2bf(v1.w);
        ((ushort4*)dst)[lane] = o0;
        ((ushort4*)dst)[lane + 64] = o1;
        float s = v0.x*v0.x + v0.y*v0.y + v0.z*v0.z + v0.w*v0.w
                + v1.x*v1.x + v1.y*v1.y + v1.z*v1.z + v1.w*v1.w;
        #pragma unroll
        for (int m = 1; m < 64; m <<= 1) s += __shfl_xor(s, m, 64);
        if (lane == 0) { if (isA) xsq[r] = s; else wsq[r - MROWS] = s; }
    }
}

// ===================== main min-pass GEMM: counted-vmcnt deep pipeline =====================
// 512 blocks = 256 row-tiles x 2 code-halves; 2 blocks/CU. 4 waves (2M x 2N), wave 32x64.
// A persistent in registers. B: 5-slot LDS ring, prefetch depth 3, s_waitcnt vmcnt(6) + raw barrier.
// approx dist = fl(-2 * dot_bf16); wsq folded into MARGIN. Per-ct minima -> LDS, flushed once.
__global__ __launch_bounds__(256, 2) void minpass_k(
    const unsigned short* __restrict__ Abf,
    const unsigned short* __restrict__ Wbf,
    float* __restrict__ partmin2)
{
    __shared__ __align__(16) unsigned short Bs[5][4096];   // ring: [slot][code*32 + k]  40KB
    __shared__ __align__(16) float pm[4096];               // [row_local][ct*2+wn]       16KB
    __shared__ __align__(16) char dmy[4096];               // tail dummy-load sink        4KB

    const int t    = threadIdx.x;
    const int lane = t & 63;
    const int w    = t >> 6;
    const int wm   = w >> 1, wn = w & 1;
    const int rt   = (int)blockIdx.x >> 1;
    const int half = (int)blockIdx.x & 1;      // even XCDs half 0, odd half 1 (L2-fit 4MB)
    const int r0   = rt * 64;

    // A fragments in registers (statically indexed; kc loop fully unrolled)
    short8 Areg[16][2];
    {
        const unsigned short* ap0 = Abf + (size_t)(r0 + wm * 32 + (lane & 15)) * DIMD + (lane >> 4) * 8;
        const unsigned short* ap1 = ap0 + (size_t)16 * DIMD;
        #pragma unroll
        for (int kc = 0; kc < 16; ++kc) {
            Areg[kc][0] = *(const short8*)(ap0 + kc * 32);
            Areg[kc][1] = *(const short8*)(ap1 + kc * 32);
        }
    }

    const unsigned short* Wb = Wbf + (size_t)half * 4096 * DIMD;
    const int srow = t >> 2;          // staged code row 0..63 (+64 for 2nd load)
    const int skof = (t & 3) * 8;     // k slot within 32-k chunk

    // prologue: stage chunks 0..2 into slots 0..2 (6 loads outstanding)
    #pragma unroll
    for (int c = 0; c < 3; ++c) {
        const unsigned short* s0 = Wb + (size_t)(srow) * DIMD + c * 32 + skof;   // ct=0, kc=c
        gload16(s0, &Bs[c][t * 8]);
        gload16(s0 + (size_t)64 * DIMD, &Bs[c][2048 + t * 8]);
    }

    int pfs = 3, rds = 0;

    f32x4 acc[2][4];
    #pragma unroll
    for (int mi = 0; mi < 2; ++mi)
        #pragma unroll
        for (int ni = 0; ni < 4; ++ni) acc[mi][ni] = (f32x4){0.f, 0.f, 0.f, 0.f};

    for (int ct = 0; ct < 32; ++ct) {
        #pragma unroll
        for (int kc = 0; kc < 16; ++kc) {
            // issue prefetch for chunk n = ct*16 + kc + 3 (uniform 2 loads/chunk; dummies at tail)
            const int n = ct * 16 + kc + 3;
            if (n < 512) {
                const unsigned short* s0 = Wb + (size_t)((n >> 4) * 128 + srow) * DIMD + (n & 15) * 32 + skof;
                gload16(s0, &Bs[pfs][t * 8]);
                gload16(s0 + (size_t)64 * DIMD, &Bs[pfs][2048 + t * 8]);
            } else {
                gload16(Wb + skof, &dmy[t * 16]);
                gload16(Wb + skof, &dmy[t * 16]);
            }
            pfs = (pfs == 4) ? 0 : pfs + 1;

            // counted wait: retire chunk (ct*16+kc); 6 loads (3 chunks) stay in flight
            asm volatile("s_waitcnt vmcnt(6)\n\ts_barrier" ::: "memory");

            const unsigned short* bb = &Bs[rds][0];
            short8 b[4];
            #pragma unroll
            for (int ni = 0; ni < 4; ++ni)
                b[ni] = *(const short8*)&bb[(wn * 64 + ni * 16 + (lane & 15)) * 32 + (lane >> 4) * 8];
            #pragma unroll
            for (int mi = 0; mi < 2; ++mi)
                #pragma unroll
                for (int ni = 0; ni < 4; ++ni)
                    acc[mi][ni] = __builtin_amdgcn_mfma_f32_16x16x32_bf16(Areg[kc][mi], b[ni], acc[mi][ni], 0, 0, 0);
            rds = (rds == 4) ? 0 : rds + 1;
        }

        // per-ct epilogue: wave-local (no barrier, no vmem). pm = -2*max(acc) = min over codes of fl(-2*acc)
        #pragma unroll
        for (int mi = 0; mi < 2; ++mi) {
            #pragma unroll
            for (int reg = 0; reg < 4; ++reg) {
                float mx = fmaxf(fmaxf(acc[mi][0][reg], acc[mi][1][reg]),
                                 fmaxf(acc[mi][2][reg], acc[mi][3][reg]));
                #pragma unroll
                for (int s = 1; s < 16; s <<= 1) mx = fmaxf(mx, __shfl_xor(mx, s, 64));
                if ((lane & 15) == 0)
                    pm[(wm * 32 + mi * 16 + (lane >> 4) * 4 + reg) * 64 + ct * 2 + wn] = -2.0f * mx;
            }
        }
        #pragma unroll
        for (int mi = 0; mi < 2; ++mi)
            #pragma unroll
            for (int ni = 0; ni < 4; ++ni) acc[mi][ni] = (f32x4){0.f, 0.f, 0.f, 0.f};
    }

    __syncthreads();   // full drain OK: once per kernel
    // flush pm -> partmin2[r][half*64 + c]
    const int rl = t >> 2, cs = (t & 3) * 16;
    #pragma unroll
    for (int j = 0; j < 4; ++j) {
        f32x4 v = *(const f32x4*)&pm[rl * 64 + cs + j * 4];
        *(f32x4*)&partmin2[(size_t)(r0 + rl) * 128 + half * 64 + cs + j * 4] = v;
    }
}

// ===================== qualify: rowmin/thr, block-aggregated bucket append =====================
__global__ __launch_bounds__(256) void qualify_k(const float* __restrict__ partmin2,
                                                 float* __restrict__ rowthr,
                                                 unsigned int* __restrict__ ctcnt,
                                                 unsigned short* __restrict__ ctrows,
                                                 unsigned long long* __restrict__ res)
{
    __shared__ unsigned cntA[64], baseL[64], cntB[64];
    const int t = threadIdx.x;
    const int r = blockIdx.x * 256 + t;   // grid 64

    if (t < 64) { cntA[t] = 0u; cntB[t] = 0u; }

    const f32x4* p = (const f32x4*)(partmin2 + (size_t)r * 128);
    float m = INFINITY;
    for (int i = 0; i < 32; ++i) {
        f32x4 x = p[i];
        m = fminf(fminf(fminf(x[0], x[1]), fminf(x[2], x[3])), m);
    }
    const float thr = m + MARGIN;
    rowthr[r] = thr;
    res[r] = ~0ull;

    unsigned long long qm = 0ull;
    for (int i = 0; i < 32; ++i) {
        f32x4 x = p[i];
        if (fminf(x[0], x[1]) <= thr) qm |= 1ull << (2 * i);
        if (fminf(x[2], x[3]) <= thr) qm |= 1ull << (2 * i + 1);
    }
    __syncthreads();
    unsigned long long mm = qm;
    while (mm) {
        const int tile = __ffsll((long long)mm) - 1;
        mm &= mm - 1;
        atomicAdd(&cntA[tile], 1u);
    }
    __syncthreads();
    if (t < 64) baseL[t] = cntA[t] ? atomicAdd(&ctcnt[t], cntA[t]) : 0u;
    __syncthreads();
    mm = qm;
    while (mm) {
        const int tile = __ffsll((long long)mm) - 1;
        mm &= mm - 1;
        const unsigned pos = baseL[tile] + atomicAdd(&cntB[tile], 1u);
        ctrows[tile * 16384 + pos] = (unsigned short)r;
    }
}

// ===================== sparse candidate GEMM (block-aggregated list append) =====================
__global__ __launch_bounds__(256) void cand_k(
    const unsigned short* __restrict__ Abf,
    const unsigned short* __restrict__ Wbf,
    const float* __restrict__ rowthr,
    const unsigned int* __restrict__ ctcnt,
    const unsigned short* __restrict__ ctrows,
    unsigned int* __restrict__ list,
    unsigned int* __restrict__ gcount)
{
    __shared__ __align__(16) unsigned short As[2][4096];
    __shared__ __align__(16) unsigned short Bs[2][4096];
    __shared__ int ids_lds[128];
    __shared__ float thr_lds[128];
    __shared__ unsigned wtot[4];
    __shared__ unsigned gb_lds;

    const int T = blockIdx.x;                  // tile 0..63, codes T*128..T*128+127
    unsigned n = ctcnt[T]; if (n > 16384u) n = 16384u;
    const unsigned base = blockIdx.y * 128;
    if (base >= n) return;

    const int t    = threadIdx.x;
    const int lane = t & 63;
    const int w    = t >> 6;
    const int wm   = w >> 1, wn = w & 1;
    const int c0   = T * 128;

    if (t < 128) {
        const int g = (base + t < n) ? (int)ctrows[T * 16384 + base + t] : -1;
        ids_lds[t] = (g < 0) ? 0 : g;
        thr_lds[t] = (g < 0) ? -INFINITY : rowthr[g];
    }
    __syncthreads();

    const int inst0 = w * 2;
    const int lrow0 = inst0 * 16 + (lane >> 2);
    const int kof   = (lane & 3) * 8;
    const unsigned short* aSrc0 = Abf + (size_t)ids_lds[lrow0] * DIMD + kof;
    const unsigned short* aSrc1 = Abf + (size_t)ids_lds[lrow0 + 16] * DIMD + kof;
    const unsigned short* bSrc0 = Wbf + (size_t)(c0 + lrow0) * DIMD + kof;
    const unsigned short* bSrc1 = bSrc0 + (size_t)16 * DIMD;

    f32x4 acc[4][4];
    #pragma unroll
    for (int mi = 0; mi < 4; ++mi)
        #pragma unroll
        for (int ni = 0; ni < 4; ++ni) acc[mi][ni] = (f32x4){0.f, 0.f, 0.f, 0.f};

    gload16(aSrc0, &As[0][inst0 * 512]);
    gload16(aSrc1, &As[0][(inst0 + 1) * 512]);
    gload16(bSrc0, &Bs[0][inst0 * 512]);
    gload16(bSrc1, &Bs[0][(inst0 + 1) * 512]);

    int cur = 0;
    for (int kc = 0; kc < 16; ++kc) {
        __syncthreads();
        if (kc + 1 < 16) {
            const int nb = cur ^ 1;
            const int ke = (kc + 1) * 32;
            gload16(aSrc0 + ke, &As[nb][inst0 * 512]);
            gload16(aSrc1 + ke, &As[nb][(inst0 + 1) * 512]);
            gload16(bSrc0 + ke, &Bs[nb][inst0 * 512]);
            gload16(bSrc1 + ke, &Bs[nb][(inst0 + 1) * 512]);
        }
        const int ko = (lane >> 4) * 8;
        short8 a[4], b[4];
        #pragma unroll
        for (int mi = 0; mi < 4; ++mi)
            a[mi] = *(const short8*)&As[cur][(wm * 64 + mi * 16 + (lane & 15)) * 32 + ko];
        #pragma unroll
        for (int ni = 0; ni < 4; ++ni)
            b[ni] = *(const short8*)&Bs[cur][(wn * 64 + ni * 16 + (lane & 15)) * 32 + ko];
        #pragma unroll
        for (int mi = 0; mi < 4; ++mi)
            #pragma unroll
            for (int ni = 0; ni < 4; ++ni)
                acc[mi][ni] = __builtin_amdgcn_mfma_f32_16x16x32_bf16(a[mi], b[ni], acc[mi][ni], 0, 0, 0);
        __syncthreads();
        cur ^= 1;
    }

    // phase A: count hits (approx = fl(-2*acc), consistent with minpass)
    unsigned nh = 0;
    #pragma unroll
    for (int mi = 0; mi < 4; ++mi)
        #pragma unroll
        for (int reg = 0; reg < 4; ++reg) {
            const float thr = thr_lds[wm * 64 + mi * 16 + (lane >> 4) * 4 + reg];
            #pragma unroll
            for (int ni = 0; ni < 4; ++ni)
                if (-2.0f * acc[mi][ni][reg] <= thr) ++nh;
        }

    unsigned pfx = nh;
    #pragma unroll
    for (int s = 1; s < 64; s <<= 1) {
        unsigned v = __shfl_up(pfx, s, 64);
        if (lane >= s) pfx += v;
    }
    if (lane == 63) wtot[w] = pfx;
    __syncthreads();
    if (t == 0) {
        const unsigned tot = wtot[0] + wtot[1] + wtot[2] + wtot[3];
        gb_lds = tot ? atomicAdd(gcount, tot) : 0u;
    }
    __syncthreads();
    unsigned wb = 0;
    #pragma unroll
    for (int i = 0; i < 4; ++i) if (i < w) wb += wtot[i];
    unsigned myoff = gb_lds + wb + pfx - nh;   // exclusive offset

    #pragma unroll
    for (int mi = 0; mi < 4; ++mi)
        #pragma unroll
        for (int reg = 0; reg < 4; ++reg) {
            const int row_l = wm * 64 + mi * 16 + (lane >> 4) * 4 + reg;
            const float thr = thr_lds[row_l];
            #pragma unroll
            for (int ni = 0; ni < 4; ++ni) {
                if (-2.0f * acc[mi][ni][reg] <= thr) {
                    const unsigned k = c0 + wn * 64 + ni * 16 + (lane & 15);
                    if (myoff < CAP)
                        list[myoff] = ((unsigned)ids_lds[row_l] << 13) | k;
                    ++myoff;
                }
            }
        }
}

// ===================== fp64-exact refine (bit-exact carryover) =====================
__global__ __launch_bounds__(256) void refine_k(const float* __restrict__ A,
                                                const float* __restrict__ W,
                                                const float* __restrict__ xsq,
                                                const float* __restrict__ wsq,
                                                const unsigned* __restrict__ list,
                                                const unsigned* __restrict__ gcount,
                                                unsigned long long* __restrict__ res)
{
    const int lane = threadIdx.x & 63;
    const int wid  = (blockIdx.x * 256 + threadIdx.x) >> 6;
    const int nw   = (gridDim.x * 256) >> 6;
    unsigned n = *gcount;
    if (n > CAP) n = CAP;
    for (unsigned i = wid; i < n; i += nw) {
        const unsigned pk = list[i];
        const unsigned row = pk >> 13, k = pk & 8191u;
        const float4* xp = (const float4*)(A + (size_t)row * DIMD);
        const float4* wp = (const float4*)(W + (size_t)k * DIMD);
        const float4 x0 = xp[lane * 2], x1 = xp[lane * 2 + 1];
        const float4 w0 = wp[lane * 2], w1 = wp[lane * 2 + 1];
        double s = (double)x0.x * w0.x + (double)x0.y * w0.y
                 + (double)x0.z * w0.z + (double)x0.w * w0.w
                 + (double)x1.x * w1.x + (double)x1.y * w1.y
                 + (double)x1.z * w1.z + (double)x1.w * w1.w;
        #pragma unroll
        for (int m = 1; m < 64; m <<= 1) s += __shfl_xor(s, m, 64);
        if (lane == 0) {
            const float Df = (float)s;
            const float dist = (xsq[row] + wsq[k]) - 2.0f * Df;
            const unsigned long long p =
                ((unsigned long long)__float_as_uint(dist) << 32) | (unsigned long long)k;
            atomicMin(res + row, p);
        }
    }
}

__global__ __launch_bounds__(256) void finish_k(const unsigned long long* __restrict__ res,
                                                int* __restrict__ idxo,
                                                float* __restrict__ out_ids)
{
    const int r = blockIdx.x * 256 + threadIdx.x;
    const int id = (int)(res[r] & 8191ull);
    idxo[r] = id;
    out_ids[r] = (float)id;
}

// ===================== outputs: gather + losses (bit-exact carryovers) =====================
__global__ __launch_bounds__(256) void gather_k(const float* __restrict__ A,
                                                const float* __restrict__ W,
                                                const int* __restrict__ idx,
                                                float* __restrict__ out_zq,
                                                double* __restrict__ partial)
{
    __shared__ double wsum[4];
    const int t   = threadIdx.x;
    const int row = blockIdx.x * 2 + (t >> 7);
    const int col = t & 127;
    const int id  = idx[row];
    const float4 ze = ((const float4*)(A + (size_t)row * DIMD))[col];
    const float4 zq = ((const float4*)(W + (size_t)id  * DIMD))[col];
    float4 o;
    o.x = ze.x + (zq.x - ze.x);
    o.y = ze.y + (zq.y - ze.y);
    o.z = ze.z + (zq.z - ze.z);
    o.w = ze.w + (zq.w - ze.w);
    ((float4*)(out_zq + (size_t)row * DIMD))[col] = o;
    const float dx = zq.x - ze.x, dy = zq.y - ze.y, dz = zq.z - ze.z, dw = zq.w - ze.w;
    double s = (double)dx*dx + (double)dy*dy + (double)dz*dz + (double)dw*dw;
    #pragma unroll
    for (int m = 1; m < 64; m <<= 1) s += __shfl_xor(s, m, 64);
    if ((t & 63) == 0) wsum[t >> 6] = s;
    __syncthreads();
    if (t == 0) partial[blockIdx.x] = (wsum[0] + wsum[1]) + (wsum[2] + wsum[3]);
}

__global__ __launch_bounds__(256) void fin_k(const double* __restrict__ partial,
                                             float* __restrict__ outs)
{
    __shared__ double wsum[4];
    const int t = threadIdx.x;
    double s = 0.0;
    for (int i = 0; i < 32; ++i) s += partial[t + 256 * i];
    #pragma unroll
    for (int m = 1; m < 64; m <<= 1) s += __shfl_xor(s, m, 64);
    if ((t & 63) == 0) wsum[t >> 6] = s;
    __syncthreads();
    if (t == 0) {
        const double tot = (wsum[0] + wsum[1]) + (wsum[2] + wsum[3]);
        const double mse = tot / (double)((size_t)MROWS * DIMD);
        const float mf = (float)mse;
        const float vq = (float)(mse * 1.25);
        outs[0] = vq; outs[1] = mf; outs[2] = mf; outs[3] = 0.0f; outs[4] = vq;
    }
}

// ===================== launch =====================

extern "C" void kernel_launch(void* const* d_in, const int* in_sizes, int n_in,
                              void* d_out, int out_size, void* d_ws, size_t ws_size,
                              hipStream_t stream)
{
    const float* A = (const float*)d_in[0];
    const float* W = (const float*)d_in[1];

    char* ws = (char*)d_ws;
    unsigned short* Abf = (unsigned short*)(ws + OFF_ABF);
    unsigned short* Wbf = (unsigned short*)(ws + OFF_WBF);
    float*  xsq     = (float*)(ws + OFF_XSQ);
    float*  wsq     = (float*)(ws + OFF_WSQ);
    float*  rowthr  = (float*)(ws + OFF_THR);
    float*  partmin2= (float*)(ws + OFF_PM2);
    unsigned long long* res = (unsigned long long*)(ws + OFF_RES);
    unsigned int* ctcnt     = (unsigned int*)(ws + OFF_CTCNT);
    unsigned int* gcount    = (unsigned int*)(ws + OFF_GCNT);
    unsigned short* ctrows  = (unsigned short*)(ws + OFF_CTROWS);
    unsigned int* list      = (unsigned int*)(ws + OFF_LIST);
    double* partial = (double*)(ws + OFF_PARTIAL);
    int*    idx     = (int*)(ws + OFF_IDX);

    float* out_zq  = (float*)d_out;
    float* out_ids = out_zq + (size_t)MROWS * DIMD;
    float* out_sc  = out_ids + MROWS;

    cvt2_k<<<512, 256, 0, stream>>>(A, W, Abf, Wbf, xsq, wsq, ctcnt, gcount);
    minpass_k<<<512, 256, 0, stream>>>(Abf, Wbf, partmin2);
    qualify_k<<<64, 256, 0, stream>>>(partmin2, rowthr, ctcnt, ctrows, res);
    cand_k<<<dim3(64, 128), 256, 0, stream>>>(Abf, Wbf, rowthr, ctcnt, ctrows, list, gcount);
    refine_k<<<512, 256, 0, stream>>>(A, W, xsq, wsq, list, gcount, res);
    finish_k<<<64, 256, 0, stream>>>(res, idx, out_ids);
    gather_k<<<8192, 256, 0, stream>>>(A, W, idx, out_zq, partial);
    fin_k<<<1, 256, 0, stream>>>(partial, out_sc);
}